// Round 1
// baseline (491.008 us; speedup 1.0000x reference)
//
#include <hip/hip_runtime.h>
#include <cstdint>
#include <cstddef>

typedef short bf16x8 __attribute__((ext_vector_type(8)));
typedef float f32x4 __attribute__((ext_vector_type(4)));

// ---- problem constants ----
// B=8, H=W=128, C=256, heads=8, hd=32, ws=8, shift=4, N=64 tokens/window,
// 16x16 windows/image, 2048 windows total.

// ---- workspace layout (byte offsets) ----
#define WS_QKVW   0u          // bf16 [768][256]
#define WS_PROJW  393216u     // bf16 [256][256]
#define WS_QKVB   524288u     // f32  [768]  (q_bias, 0, v_bias)
#define WS_SCALE  527360u     // f32  [8]    exp(min(logit_scale, ln 100))
#define WS_BT     527392u     // f32  [225][8] cpb table
#define WS_BIAS   534592u     // f32  [8][4][4][64][4]  (MFMA C-frag swizzled)
// total needed: 665664 bytes

// ---- LDS layout (ushort units) ----
#define XS_US   0          // bf16 [64][264]  x-window; later attn_out (reused)
#define QK_US   16896      // per head 5120 us: q[64][40] @+0, k[64][40] @+2560; P overlays [64][72]
#define VS_US   57856      // per head 2304 us: v^T [32][72]
#define SMEM_US 76288
#define SMEM_BYTES (SMEM_US * 2)   // 152576 bytes

__device__ __forceinline__ unsigned short f2b(float f) {
  union { float f; unsigned int u; } v; v.f = f;
  return (unsigned short)((v.u + 0x7FFFu + ((v.u >> 16) & 1u)) >> 16);
}
__device__ __forceinline__ float b2f(unsigned short h) {
  union { unsigned int u; float f; } v; v.u = ((unsigned int)h) << 16;
  return v.f;
}

// ---------------- prep kernels ----------------

__global__ void prep_weights(const float* __restrict__ qkv_w,
                             const float* __restrict__ q_bias,
                             const float* __restrict__ v_bias,
                             const float* __restrict__ logit_scale,
                             const float* __restrict__ proj_w,
                             unsigned char* __restrict__ ws) {
  int gid = blockIdx.x * 256 + threadIdx.x;            // 0 .. 196607
  unsigned short* qw = (unsigned short*)(ws + WS_QKVW);
  unsigned short* pw = (unsigned short*)(ws + WS_PROJW);
  if (gid < 196608) qw[gid] = f2b(qkv_w[gid]);
  if (gid < 65536)  pw[gid] = f2b(proj_w[gid]);
  if (gid < 768) {
    float v = 0.f;
    if (gid < 256) v = q_bias[gid];
    else if (gid >= 512) v = v_bias[gid - 512];
    ((float*)(ws + WS_QKVB))[gid] = v;
  }
  if (gid < 8) {
    float ls = logit_scale[gid];
    ((float*)(ws + WS_SCALE))[gid] = __expf(fminf(ls, 4.605170185988091f));
  }
}

__global__ void prep_cpb(const float* __restrict__ w1, const float* __restrict__ b1,
                         const float* __restrict__ w2, unsigned char* __restrict__ ws) {
  __shared__ float hid[512];
  const int r = blockIdx.x;            // 0..224
  const int dh = r / 15, dw = r % 15;
  float t0 = ((float)(dh - 7)) / 7.0f * 8.0f;
  float t1 = ((float)(dw - 7)) / 7.0f * 8.0f;
  float a0 = log2f(fabsf(t0) + 1.0f) / 3.0f;
  float a1 = log2f(fabsf(t1) + 1.0f) / 3.0f;
  t0 = (t0 < 0.f) ? -a0 : a0;
  t1 = (t1 < 0.f) ? -a1 : a1;
  const int j = threadIdx.x;           // 0..511
  float h = t0 * w1[2 * j] + t1 * w1[2 * j + 1] + b1[j];
  hid[j] = fmaxf(h, 0.f);
  __syncthreads();
  const int wave = j >> 6, lane = j & 63;   // wave == head
  float p = 0.f;
  for (int jj = lane; jj < 512; jj += 64) p += hid[jj] * w2[wave * 512 + jj];
  #pragma unroll
  for (int off = 32; off > 0; off >>= 1) p += __shfl_down(p, off, 64);
  if (lane == 0) ((float*)(ws + WS_BT))[r * 8 + wave] = p;
}

__global__ void prep_bias(unsigned char* __restrict__ ws) {
  int u = blockIdx.x * 256 + threadIdx.x;   // 0..32767
  int reg = u & 3;
  int lane = (u >> 2) & 63;
  int nt = (u >> 8) & 3;
  int mt = (u >> 10) & 3;
  int h = (u >> 12);
  int i = mt * 16 + (lane >> 4) * 4 + reg;
  int jx = nt * 16 + (lane & 15);
  int idx = ((i >> 3) - (jx >> 3) + 7) * 15 + ((i & 7) - (jx & 7) + 7);
  float xv = ((const float*)(ws + WS_BT))[idx * 8 + h];
  ((float*)(ws + WS_BIAS))[u] = 16.0f / (1.0f + __expf(-xv));
}

// ---------------- main fused kernel ----------------

__launch_bounds__(512, 2)
__global__ void swin_main(const float* __restrict__ x,
                          const unsigned char* __restrict__ ws,
                          float* __restrict__ out,
                          const float* __restrict__ proj_b) {
  extern __shared__ unsigned short sm[];
  const int tid = threadIdx.x;
  const int wave = tid >> 6;
  const int lane = tid & 63;
  const int quad = lane >> 4;
  const int l15 = lane & 15;

  const int blk = blockIdx.x;
  const int b = blk >> 8;
  const int win = blk & 255;
  const int wr = win >> 4;
  const int wc = win & 15;

  const unsigned short* qkvw = (const unsigned short*)(ws + WS_QKVW);
  const unsigned short* projw = (const unsigned short*)(ws + WS_PROJW);
  const float* qkvb = (const float*)(ws + WS_QKVB);
  const float* scales = (const float*)(ws + WS_SCALE);
  const float* bias_sw = (const float*)(ws + WS_BIAS);

  // ---- phase 0: gather shifted window -> xs bf16 [64][264]
  {
    const int t = tid >> 3;          // token 0..63
    const int cg = tid & 7;          // channel group
    const int rw = t >> 3, cw = t & 7;
    const int gr = (wr * 8 + rw + 4) & 127;
    const int gc = (wc * 8 + cw + 4) & 127;
    const float* src = x + ((size_t)b * 16384 + gr * 128 + gc) * 256 + cg * 32;
    unsigned short* dst = sm + XS_US + t * 264 + cg * 32;
    #pragma unroll
    for (int kk = 0; kk < 4; ++kk) {
      f32x4 a = *(const f32x4*)(src + kk * 8);
      f32x4 c = *(const f32x4*)(src + kk * 8 + 4);
      union { bf16x8 v; unsigned short u[8]; } pk;
      #pragma unroll
      for (int e = 0; e < 4; ++e) { pk.u[e] = f2b(a[e]); pk.u[4 + e] = f2b(c[e]); }
      *(bf16x8*)(dst + kk * 8) = pk.v;
    }
  }
  __syncthreads();

  // ---- phase 1: QKV GEMM  (64x768 = xs[64x256] @ Wqkv^T), wave owns 96 cols
  {
    f32x4 acc[4][6];
    #pragma unroll
    for (int mt = 0; mt < 4; ++mt)
      #pragma unroll
      for (int nt = 0; nt < 6; ++nt) acc[mt][nt] = f32x4{0.f, 0.f, 0.f, 0.f};
    const int ncol0 = wave * 96;
    for (int k0 = 0; k0 < 256; k0 += 32) {
      bf16x8 afr[4];
      #pragma unroll
      for (int mt = 0; mt < 4; ++mt)
        afr[mt] = *(const bf16x8*)(sm + XS_US + (mt * 16 + l15) * 264 + k0 + quad * 8);
      #pragma unroll
      for (int nt = 0; nt < 6; ++nt) {
        const int n = ncol0 + nt * 16 + l15;
        bf16x8 bfr = *(const bf16x8*)(qkvw + n * 256 + k0 + quad * 8);
        #pragma unroll
        for (int mt = 0; mt < 4; ++mt)
          acc[mt][nt] = __builtin_amdgcn_mfma_f32_16x16x32_bf16(afr[mt], bfr, acc[mt][nt], 0, 0, 0);
      }
    }
    // epilogue: +bias, scatter into q/k (token-major) and v (transposed)
    #pragma unroll
    for (int nt = 0; nt < 6; ++nt) {
      const int n0 = ncol0 + nt * 16;
      const float bias = qkvb[n0 + l15];
      const int which = n0 >> 8;            // 0=q 1=k 2=v
      const int head = (n0 & 255) >> 5;
      const int chan = (n0 & 31) + l15;     // 0..31 (tile never straddles a head)
      #pragma unroll
      for (int mt = 0; mt < 4; ++mt) {
        const int tok0 = mt * 16 + quad * 4;
        if (which == 2) {
          union { unsigned short u[4]; unsigned long long ll; } pk;
          #pragma unroll
          for (int r = 0; r < 4; ++r) pk.u[r] = f2b(acc[mt][nt][r] + bias);
          *(unsigned long long*)(sm + VS_US + head * 2304 + chan * 72 + tok0) = pk.ll;
        } else {
          unsigned short* q = sm + QK_US + head * 5120 + which * 2560 + chan;
          #pragma unroll
          for (int r = 0; r < 4; ++r) q[(tok0 + r) * 40] = f2b(acc[mt][nt][r] + bias);
        }
      }
    }
  }
  __syncthreads();

  // ---- phase 1.5: cosine-normalize q (fold per-head scale) and k, in place
  {
    #pragma unroll
    for (int it = 0; it < 2; ++it) {
      const int task = tid + it * 512;      // 0..1023
      const int isk = task >> 9;            // 0=q 1=k
      const int rem = task & 511;
      const int head = rem >> 6;
      const int tok = rem & 63;
      unsigned short* p = sm + QK_US + head * 5120 + isk * 2560 + tok * 40;
      float vals[32];
      float ss = 0.f;
      #pragma unroll
      for (int c8 = 0; c8 < 4; ++c8) {
        bf16x8 vv = *(const bf16x8*)(p + c8 * 8);
        #pragma unroll
        for (int e = 0; e < 8; ++e) {
          float f = b2f((unsigned short)vv[e]);
          vals[c8 * 8 + e] = f;
          ss += f * f;
        }
      }
      float inv = 1.0f / fmaxf(sqrtf(ss), 1e-12f);
      if (isk == 0) inv *= scales[head];
      #pragma unroll
      for (int c8 = 0; c8 < 4; ++c8) {
        union { bf16x8 v; unsigned short u[8]; } pk;
        #pragma unroll
        for (int e = 0; e < 8; ++e) pk.u[e] = f2b(vals[c8 * 8 + e] * inv);
        *(bf16x8*)(p + c8 * 8) = pk.v;
      }
    }
  }
  __syncthreads();

  // ---- phase 2: attention; wave == head
  float rinv[4][4];
  f32x4 o[4][2];
  {
    const int h = wave;
    const unsigned short* qb = sm + QK_US + h * 5120;
    const unsigned short* kb = qb + 2560;
    f32x4 s[4][4];
    bf16x8 aq[4];
    #pragma unroll
    for (int mt = 0; mt < 4; ++mt)
      aq[mt] = *(const bf16x8*)(qb + (mt * 16 + l15) * 40 + quad * 8);
    #pragma unroll
    for (int nt = 0; nt < 4; ++nt) {
      bf16x8 bk = *(const bf16x8*)(kb + (nt * 16 + l15) * 40 + quad * 8);
      #pragma unroll
      for (int mt = 0; mt < 4; ++mt)
        s[mt][nt] = __builtin_amdgcn_mfma_f32_16x16x32_bf16(aq[mt], bk, f32x4{0.f, 0.f, 0.f, 0.f}, 0, 0, 0);
    }
    // + relative-position bias (pre-swizzled) and shift mask (inline)
    const bool has_mask = (wr == 15) || (wc == 15);
    #pragma unroll
    for (int mt = 0; mt < 4; ++mt) {
      #pragma unroll
      for (int nt = 0; nt < 4; ++nt) {
        f32x4 bv = *(const f32x4*)(bias_sw + (size_t)(((h * 4 + mt) * 4 + nt) * 64 + lane) * 4);
        #pragma unroll
        for (int r = 0; r < 4; ++r) s[mt][nt][r] += bv[r];
        if (has_mask) {
          const int j = nt * 16 + l15;
          const int brj = (wr == 15) ? (((j >> 3) < 4) ? 1 : 2) : 0;
          const int bcj = (wc == 15) ? (((j & 7) < 4) ? 1 : 2) : 0;
          #pragma unroll
          for (int r = 0; r < 4; ++r) {
            const int i = mt * 16 + quad * 4 + r;
            const int bri = (wr == 15) ? (((i >> 3) < 4) ? 1 : 2) : 0;
            const int bci = (wc == 15) ? (((i & 7) < 4) ? 1 : 2) : 0;
            if (bri != brj || bci != bcj) s[mt][nt][r] -= 100.0f;
          }
        }
      }
    }
    // softmax over j (row lives on 16 lanes x 4 regs); keep P unnormalized
    #pragma unroll
    for (int mt = 0; mt < 4; ++mt) {
      #pragma unroll
      for (int r = 0; r < 4; ++r) {
        float m = fmaxf(fmaxf(s[mt][0][r], s[mt][1][r]), fmaxf(s[mt][2][r], s[mt][3][r]));
        #pragma unroll
        for (int off = 1; off < 16; off <<= 1) m = fmaxf(m, __shfl_xor(m, off, 64));
        float sum = 0.f;
        #pragma unroll
        for (int nt = 0; nt < 4; ++nt) {
          float p = __expf(s[mt][nt][r] - m);
          s[mt][nt][r] = p;
          sum += p;
        }
        #pragma unroll
        for (int off = 1; off < 16; off <<= 1) sum += __shfl_xor(sum, off, 64);
        rinv[mt][r] = 1.0f / sum;
      }
    }
    // P -> LDS (overlays this head's q/k region; head-private)
    unsigned short* pbuf = sm + QK_US + h * 5120;
    #pragma unroll
    for (int mt = 0; mt < 4; ++mt) {
      #pragma unroll
      for (int r = 0; r < 4; ++r) {
        const int row = mt * 16 + quad * 4 + r;
        #pragma unroll
        for (int nt = 0; nt < 4; ++nt)
          pbuf[row * 72 + nt * 16 + l15] = f2b(s[mt][nt][r]);
      }
    }
    __syncthreads();   // ordering fence before re-reading P as fragments
    #pragma unroll
    for (int mt = 0; mt < 4; ++mt)
      #pragma unroll
      for (int nc = 0; nc < 2; ++nc) o[mt][nc] = f32x4{0.f, 0.f, 0.f, 0.f};
    const unsigned short* vb = sm + VS_US + h * 2304;
    #pragma unroll
    for (int ks = 0; ks < 2; ++ks) {
      bf16x8 ap[4];
      #pragma unroll
      for (int mt = 0; mt < 4; ++mt)
        ap[mt] = *(const bf16x8*)(pbuf + (mt * 16 + l15) * 72 + ks * 32 + quad * 8);
      #pragma unroll
      for (int nc = 0; nc < 2; ++nc) {
        bf16x8 bv = *(const bf16x8*)(vb + (nc * 16 + l15) * 72 + ks * 32 + quad * 8);
        #pragma unroll
        for (int mt = 0; mt < 4; ++mt)
          o[mt][nc] = __builtin_amdgcn_mfma_f32_16x16x32_bf16(ap[mt], bv, o[mt][nc], 0, 0, 0);
      }
    }
    // O (normalized) -> attn_out bf16 [64][264] (reuses xs region)
    #pragma unroll
    for (int mt = 0; mt < 4; ++mt) {
      #pragma unroll
      for (int nc = 0; nc < 2; ++nc) {
        #pragma unroll
        for (int r = 0; r < 4; ++r) {
          const int tok = mt * 16 + quad * 4 + r;
          sm[XS_US + tok * 264 + h * 32 + nc * 16 + l15] = f2b(o[mt][nc][r] * rinv[mt][r]);
        }
      }
    }
  }
  __syncthreads();

  // ---- phase 3: proj GEMM (64x256 = attn_out @ Wp^T) + unshift scatter-store
  {
    f32x4 acc[4][2];
    #pragma unroll
    for (int mt = 0; mt < 4; ++mt)
      #pragma unroll
      for (int nt = 0; nt < 2; ++nt) acc[mt][nt] = f32x4{0.f, 0.f, 0.f, 0.f};
    const int ncol0 = wave * 32;
    for (int k0 = 0; k0 < 256; k0 += 32) {
      bf16x8 afr[4];
      #pragma unroll
      for (int mt = 0; mt < 4; ++mt)
        afr[mt] = *(const bf16x8*)(sm + XS_US + (mt * 16 + l15) * 264 + k0 + quad * 8);
      #pragma unroll
      for (int nt = 0; nt < 2; ++nt) {
        const int n = ncol0 + nt * 16 + l15;
        bf16x8 bfr = *(const bf16x8*)(projw + n * 256 + k0 + quad * 8);
        #pragma unroll
        for (int mt = 0; mt < 4; ++mt)
          acc[mt][nt] = __builtin_amdgcn_mfma_f32_16x16x32_bf16(afr[mt], bfr, acc[mt][nt], 0, 0, 0);
      }
    }
    #pragma unroll
    for (int nt = 0; nt < 2; ++nt) {
      const int col = ncol0 + nt * 16 + l15;
      const float pb = proj_b[col];
      #pragma unroll
      for (int mt = 0; mt < 4; ++mt) {
        #pragma unroll
        for (int r = 0; r < 4; ++r) {
          const int tok = mt * 16 + quad * 4 + r;
          const int rw = tok >> 3, cw = tok & 7;
          const int gr = (wr * 8 + rw + 4) & 127;
          const int gc = (wc * 8 + cw + 4) & 127;
          out[((size_t)b * 16384 + gr * 128 + gc) * 256 + col] = acc[mt][nt][r] + pb;
        }
      }
    }
  }
}

// ---------------- launch ----------------

extern "C" void kernel_launch(void* const* d_in, const int* in_sizes, int n_in,
                              void* d_out, int out_size, void* d_ws, size_t ws_size,
                              hipStream_t stream) {
  const float* x           = (const float*)d_in[0];
  const float* qkv_w       = (const float*)d_in[1];
  const float* q_bias      = (const float*)d_in[2];
  const float* v_bias      = (const float*)d_in[3];
  const float* logit_scale = (const float*)d_in[4];
  const float* cpb_w1      = (const float*)d_in[5];
  const float* cpb_b1      = (const float*)d_in[6];
  const float* cpb_w2      = (const float*)d_in[7];
  const float* proj_w      = (const float*)d_in[8];
  const float* proj_b      = (const float*)d_in[9];
  unsigned char* ws = (unsigned char*)d_ws;
  float* out = (float*)d_out;

  prep_weights<<<768, 256, 0, stream>>>(qkv_w, q_bias, v_bias, logit_scale, proj_w, ws);
  prep_cpb<<<225, 512, 0, stream>>>(cpb_w1, cpb_b1, cpb_w2, ws);
  prep_bias<<<128, 256, 0, stream>>>(ws);

  (void)hipFuncSetAttribute((const void*)swin_main,
                            hipFuncAttributeMaxDynamicSharedMemorySize, SMEM_BYTES);
  swin_main<<<2048, 512, SMEM_BYTES, stream>>>(x, ws, out, proj_b);
}